// Round 1
// baseline (289.897 us; speedup 1.0000x reference)
//
#include <hip/hip_runtime.h>
#include <hip/hip_bf16.h>

#define NN 100000
#define DD 128
#define EE 400000

typedef unsigned short u16;
typedef __attribute__((ext_vector_type(4))) float floatx4;
typedef __attribute__((ext_vector_type(8))) short shortx8;

__device__ __forceinline__ u16 f2bf(float f) {
    // round-to-nearest-even fp32 -> bf16 (inputs are finite)
    unsigned u = __float_as_uint(f);
    u += 0x7FFFu + ((u >> 16) & 1u);
    return (u16)(u >> 16);
}

// ---- degree masks: mask[dst[e]] = 1 (idempotent byte store, no atomic needed)
__global__ void mark_deg(const int* __restrict__ daa, const int* __restrict__ dab,
                         const int* __restrict__ dba,
                         unsigned char* __restrict__ maa, unsigned char* __restrict__ mab,
                         unsigned char* __restrict__ mba) {
    int e = blockIdx.x * 256 + threadIdx.x;
    if (e < EE) {
        maa[daa[e]] = 1;
        mab[dab[e]] = 1;
        mba[dba[e]] = 1;
    }
}

__global__ void make_scales(const unsigned char* __restrict__ maa,
                            const unsigned char* __restrict__ mab,
                            const unsigned char* __restrict__ mba,
                            float* __restrict__ sA, float* __restrict__ sB) {
    int n = blockIdx.x * 256 + threadIdx.x;
    if (n < NN) {
        sA[n] = (1.0f + (float)maa[n] + (float)mba[n]) * (1.0f / 3.0f);
        sB[n] = (1.0f + (float)mab[n]) * 0.5f;
    }
}

// ---- convert the 4 Wr matrices (layer0 A/B, layer1 A/B) to bf16, TRANSPOSED:
// Wt[mat][n][k] = bf16( W[mat][k][n] )  so B-fragments are contiguous in k.
__global__ void conv_wt(const float* __restrict__ Wr0, const float* __restrict__ Wr1,
                        u16* __restrict__ Wt) {
    int idx = blockIdx.x * 256 + threadIdx.x;  // 4 * 16384, exact
    int mat = idx >> 14;
    int n = (idx >> 7) & 127;
    int k = idx & 127;
    const float* W = (mat < 2) ? (Wr0 + mat * 16384) : (Wr1 + (mat - 2) * 16384);
    Wt[idx] = f2bf(W[k * 128 + n]);
}

// ---- out[m,:] = relu( scale[m] * (A[m,:] @ W + bias) )
// MFMA 16x16x32 bf16. W (transposed, bf16) staged in LDS; A-fragments loaded
// directly from global in A-operand layout (A[m=lane&15][k=quad*8+j]).
template <bool IN_BF16, bool OUT_BF16>
__global__ __launch_bounds__(256) void gemm_rowscale(
    const void* __restrict__ Ain, const u16* __restrict__ Wt,
    const float* __restrict__ bias, const float* __restrict__ scale,
    void* __restrict__ out) {
    __shared__ u16 Wlds[128 * 136];  // +8 pad per row -> no bank conflicts
    const int t = threadIdx.x;
#pragma unroll
    for (int i = 0; i < 8; ++i) {
        int idx = i * 256 + t;       // 2048 chunks of 8 bf16
        int n = idx >> 4, c8 = idx & 15;
        shortx8 v = ((const shortx8*)Wt)[idx];
        *(shortx8*)&Wlds[n * 136 + c8 * 8] = v;
    }
    __syncthreads();

    const int wave = t >> 6;
    const int lane = t & 63;
    const int quad = lane >> 4;
    const int mrow = lane & 15;
    const int m0 = blockIdx.x * 64 + wave * 16;  // this wave's 16-row strip
    const int m = m0 + mrow;
    const int msafe = (m < NN) ? m : (NN - 1);

    // A fragments for all 4 k-steps (K=128, 32 per step)
    shortx8 afrag[4];
    if constexpr (IN_BF16) {
        const u16* arow = (const u16*)Ain + (size_t)msafe * 128;
#pragma unroll
        for (int ks = 0; ks < 4; ++ks)
            afrag[ks] = *(const shortx8*)(arow + ks * 32 + quad * 8);
    } else {
        const float* arow = (const float*)Ain + (size_t)msafe * 128;
#pragma unroll
        for (int ks = 0; ks < 4; ++ks) {
            floatx4 f0 = *(const floatx4*)(arow + ks * 32 + quad * 8);
            floatx4 f1 = *(const floatx4*)(arow + ks * 32 + quad * 8 + 4);
            union { shortx8 v; u16 u[8]; } uu;
            uu.u[0] = f2bf(f0[0]); uu.u[1] = f2bf(f0[1]);
            uu.u[2] = f2bf(f0[2]); uu.u[3] = f2bf(f0[3]);
            uu.u[4] = f2bf(f1[0]); uu.u[5] = f2bf(f1[1]);
            uu.u[6] = f2bf(f1[2]); uu.u[7] = f2bf(f1[3]);
            afrag[ks] = uu.v;
        }
    }

    floatx4 acc[8];
#pragma unroll
    for (int nt = 0; nt < 8; ++nt) acc[nt] = (floatx4){0.f, 0.f, 0.f, 0.f};

#pragma unroll
    for (int ks = 0; ks < 4; ++ks) {
#pragma unroll
        for (int nt = 0; nt < 8; ++nt) {
            // B[k = quad*8+j][n = nt*16+mrow]  ==  Wt[n][k]
            shortx8 b = *(const shortx8*)&Wlds[(nt * 16 + mrow) * 136 + ks * 32 + quad * 8];
            acc[nt] = __builtin_amdgcn_mfma_f32_16x16x32_bf16(afrag[ks], b, acc[nt], 0, 0, 0);
        }
    }

    // epilogue: D[row = quad*4+r][col = lane&15]; fuse bias + row scale + relu
    float scl[4];
    int orow[4];
#pragma unroll
    for (int r = 0; r < 4; ++r) {
        orow[r] = m0 + quad * 4 + r;
        scl[r] = scale[(orow[r] < NN) ? orow[r] : (NN - 1)];
    }
#pragma unroll
    for (int nt = 0; nt < 8; ++nt) {
        int col = nt * 16 + mrow;
        float bv = bias[col];
#pragma unroll
        for (int r = 0; r < 4; ++r) {
            if (orow[r] < NN) {
                float v = (acc[nt][r] + bv) * scl[r];
                v = fmaxf(v, 0.0f);
                if constexpr (OUT_BF16)
                    ((u16*)out)[(size_t)orow[r] * 128 + col] = f2bf(v);
                else
                    ((float*)out)[(size_t)orow[r] * 128 + col] = v;
            }
        }
    }
}

extern "C" void kernel_launch(void* const* d_in, const int* in_sizes, int n_in,
                              void* d_out, int out_size, void* d_ws, size_t ws_size,
                              hipStream_t stream) {
    (void)in_sizes; (void)n_in; (void)out_size;
    // setup_inputs order:
    // 0 featA, 1 featB, 2 src_aa, 3 dst_aa, 4 src_ab, 5 dst_ab, 6 src_ba, 7 dst_ba,
    // 8 Wl0, 9 bl0, 10 Wr0, 11 br0, 12 al0, 13 ar0, 14 Wl1, 15 bl1, 16 Wr1, 17 br1, 18 al1, 19 ar1
    const float* featA = (const float*)d_in[0];
    const float* featB = (const float*)d_in[1];
    const int* dst_aa = (const int*)d_in[3];
    const int* dst_ab = (const int*)d_in[5];
    const int* dst_ba = (const int*)d_in[7];
    const float* Wr0 = (const float*)d_in[10];
    const float* br0 = (const float*)d_in[11];
    const float* Wr1 = (const float*)d_in[16];
    const float* br1 = (const float*)d_in[17];

    char* ws = (char*)d_ws;
    size_t o = 0;
    u16* Wt = (u16*)(ws + o);           o += (size_t)4 * 16384 * 2;
    float* sA = (float*)(ws + o);       o += (size_t)NN * 4;
    float* sB = (float*)(ws + o);       o += (size_t)NN * 4;
    unsigned char* masks = (unsigned char*)(ws + o); o += (size_t)3 * NN;
    o = (o + 255) & ~(size_t)255;
    u16* hA1 = (u16*)(ws + o);
    u16* hB1 = hA1 + (size_t)NN * 128;
    const bool big = ws_size >= o + (size_t)2 * NN * 128 * 2;

    float* outA = (float*)d_out;
    float* outB = outA + (size_t)NN * 128;

    hipMemsetAsync(masks, 0, (size_t)3 * NN, stream);
    mark_deg<<<(EE + 255) / 256, 256, 0, stream>>>(dst_aa, dst_ab, dst_ba,
                                                   masks, masks + NN, masks + 2 * NN);
    make_scales<<<(NN + 255) / 256, 256, 0, stream>>>(masks, masks + NN, masks + 2 * NN, sA, sB);
    conv_wt<<<256, 256, 0, stream>>>(Wr0, Wr1, Wt);

    const int gb = (NN + 63) / 64;  // 64 rows per block
    if (big) {
        // layer 1 -> bf16 intermediates in ws
        gemm_rowscale<false, true><<<gb, 256, 0, stream>>>(featA, Wt, br0, sA, hA1);
        gemm_rowscale<false, true><<<gb, 256, 0, stream>>>(featB, Wt + 16384, br0 + 128, sB, hB1);
        // layer 2 -> fp32 output
        gemm_rowscale<true, false><<<gb, 256, 0, stream>>>(hA1, Wt + 2 * 16384, br1, sA, outA);
        gemm_rowscale<true, false><<<gb, 256, 0, stream>>>(hB1, Wt + 3 * 16384, br1 + 128, sB, outB);
    } else {
        // fallback: fp32 intermediates living in d_out, layer 2 in-place
        // (safe: each wave reads exactly the rows it later writes)
        gemm_rowscale<false, false><<<gb, 256, 0, stream>>>(featA, Wt, br0, sA, outA);
        gemm_rowscale<false, false><<<gb, 256, 0, stream>>>(featB, Wt + 16384, br0 + 128, sB, outB);
        gemm_rowscale<false, false><<<gb, 256, 0, stream>>>(outA, Wt + 2 * 16384, br1, sA, outA);
        gemm_rowscale<false, false><<<gb, 256, 0, stream>>>(outB, Wt + 3 * 16384, br1 + 128, sB, outB);
    }
}

// Round 2
// 253.932 us; speedup vs baseline: 1.1416x; 1.1416x over previous
//
#include <hip/hip_runtime.h>
#include <hip/hip_bf16.h>

#define NN 100000
#define EE 400000
#define NPAD 136   // 128 + 8 u16 pad: LDS rows stride 272B -> bank rotation, no conflicts

typedef unsigned short u16;
typedef __attribute__((ext_vector_type(4))) float floatx4;
typedef __attribute__((ext_vector_type(8))) short shortx8;

__device__ __forceinline__ u16 f2bf(float f) {
    unsigned u = __float_as_uint(f);
    u += 0x7FFFu + ((u >> 16) & 1u);
    return (u16)(u >> 16);
}

// ---- prep: blocks [0,1563) mark degree masks; blocks [1563,1819) transpose+convert W
__global__ __launch_bounds__(256) void prep(
    const int* __restrict__ daa, const int* __restrict__ dab, const int* __restrict__ dba,
    unsigned char* __restrict__ masks,   // [3][NN]
    const float* __restrict__ Wr0, const float* __restrict__ Wr1,
    u16* __restrict__ Wt) {              // [4][128][128] : Wt[mat][n][k] = W[mat][k][n]
    int b = blockIdx.x;
    int t = threadIdx.x;
    if (b < (EE + 255) / 256) {
        int e = b * 256 + t;
        if (e < EE) {
            masks[daa[e]] = 1;               // idempotent byte stores, no atomics
            masks[NN + dab[e]] = 1;
            masks[2 * NN + dba[e]] = 1;
        }
    } else {
        int idx = (b - (EE + 255) / 256) * 256 + t;   // 4*16384 exact
        int mat = idx >> 14;
        int n = (idx >> 7) & 127;
        int k = idx & 127;
        const float* W = (mat < 2) ? (Wr0 + mat * 16384) : (Wr1 + (mat - 2) * 16384);
        Wt[idx] = f2bf(W[k * 128 + n]);
    }
}

// ---- fused 2-layer row-local network:
// out[m] = relu(s[m]*(relu(s[m]*(feat[m]@W0 + b0)) @ W1 + b1))
__global__ __launch_bounds__(512, 4) void fused2(
    const float* __restrict__ featA, const float* __restrict__ featB,
    const u16* __restrict__ Wt,
    const float* __restrict__ br0, const float* __restrict__ br1,
    const unsigned char* __restrict__ masks,
    float* __restrict__ out) {
    __shared__ u16 ldsW0[128 * NPAD];   // W0; reused as h1 buffer after GEMM1
    __shared__ u16 ldsW1[128 * NPAD];

    const int blocksPerType = (NN + 127) / 128;   // 782
    const int type = (blockIdx.x >= blocksPerType) ? 1 : 0;
    const int blk = blockIdx.x - type * blocksPerType;
    const float* feat = type ? featB : featA;
    const u16* W0 = Wt + type * 16384;
    const u16* W1 = Wt + (2 + type) * 16384;
    const float* b0 = br0 + type * 128;
    const float* b1 = br1 + type * 128;
    float* outp = out + (size_t)type * NN * 128;

    const int t = threadIdx.x;
    // stage both W matrices: 2048 shortx8 chunks each, 512 threads -> 4 iters
#pragma unroll
    for (int i = 0; i < 4; ++i) {
        int idx = i * 512 + t;
        int n = idx >> 4, c8 = idx & 15;
        *(shortx8*)&ldsW0[n * NPAD + c8 * 8] = ((const shortx8*)W0)[idx];
        *(shortx8*)&ldsW1[n * NPAD + c8 * 8] = ((const shortx8*)W1)[idx];
    }

    const int wave = t >> 6;          // 0..7, 16 rows each -> 128 rows/block
    const int lane = t & 63;
    const int quad = lane >> 4;
    const int mrow = lane & 15;
    const int m0 = blk * 128 + wave * 16;
    const int m = m0 + mrow;
    const int msafe = (m < NN) ? m : (NN - 1);

    // A fragments (layer 1) straight from global fp32, converted to bf16
    shortx8 afrag[4];
    {
        const float* arow = feat + (size_t)msafe * 128;
#pragma unroll
        for (int ks = 0; ks < 4; ++ks) {
            floatx4 f0 = *(const floatx4*)(arow + ks * 32 + quad * 8);
            floatx4 f1 = *(const floatx4*)(arow + ks * 32 + quad * 8 + 4);
            union { shortx8 v; u16 u[8]; } uu;
            uu.u[0] = f2bf(f0[0]); uu.u[1] = f2bf(f0[1]);
            uu.u[2] = f2bf(f0[2]); uu.u[3] = f2bf(f0[3]);
            uu.u[4] = f2bf(f1[0]); uu.u[5] = f2bf(f1[1]);
            uu.u[6] = f2bf(f1[2]); uu.u[7] = f2bf(f1[3]);
            afrag[ks] = uu.v;
        }
    }

    // per-row scale from degree masks (same scale both layers — edges fixed)
    float scl[4];
#pragma unroll
    for (int r = 0; r < 4; ++r) {
        int rr = m0 + quad * 4 + r;
        rr = (rr < NN) ? rr : (NN - 1);
        scl[r] = type ? (1.0f + (float)masks[NN + rr]) * 0.5f
                      : (1.0f + (float)masks[rr] + (float)masks[2 * NN + rr]) * (1.0f / 3.0f);
    }

    __syncthreads();   // W staged

    // ---- GEMM1: h1 = relu(s*(A@W0 + b0))
    floatx4 acc[8];
#pragma unroll
    for (int nt = 0; nt < 8; ++nt) acc[nt] = (floatx4){0.f, 0.f, 0.f, 0.f};
#pragma unroll
    for (int ks = 0; ks < 4; ++ks)
#pragma unroll
        for (int nt = 0; nt < 8; ++nt) {
            shortx8 bfr = *(const shortx8*)&ldsW0[(nt * 16 + mrow) * NPAD + ks * 32 + quad * 8];
            acc[nt] = __builtin_amdgcn_mfma_f32_16x16x32_bf16(afrag[ks], bfr, acc[nt], 0, 0, 0);
        }

    __syncthreads();   // all W0 reads complete before overwrite

    // epilogue1 -> h1 into ldsW0 (row-major padded), C-layout: D[quad*4+r][nt*16+mrow]
#pragma unroll
    for (int nt = 0; nt < 8; ++nt) {
        int col = nt * 16 + mrow;
        float bv = b0[col];
#pragma unroll
        for (int r = 0; r < 4; ++r) {
            float v = fmaxf((acc[nt][r] + bv) * scl[r], 0.0f);
            ldsW0[(wave * 16 + quad * 4 + r) * NPAD + col] = f2bf(v);
        }
    }
    __syncthreads();

    // A fragments (layer 2) from LDS
    shortx8 a2[4];
#pragma unroll
    for (int ks = 0; ks < 4; ++ks)
        a2[ks] = *(const shortx8*)&ldsW0[(wave * 16 + mrow) * NPAD + ks * 32 + quad * 8];

    // ---- GEMM2: out = relu(s*(h1@W1 + b1))
    floatx4 acc2[8];
#pragma unroll
    for (int nt = 0; nt < 8; ++nt) acc2[nt] = (floatx4){0.f, 0.f, 0.f, 0.f};
#pragma unroll
    for (int ks = 0; ks < 4; ++ks)
#pragma unroll
        for (int nt = 0; nt < 8; ++nt) {
            shortx8 bfr = *(const shortx8*)&ldsW1[(nt * 16 + mrow) * NPAD + ks * 32 + quad * 8];
            acc2[nt] = __builtin_amdgcn_mfma_f32_16x16x32_bf16(a2[ks], bfr, acc2[nt], 0, 0, 0);
        }

#pragma unroll
    for (int nt = 0; nt < 8; ++nt) {
        int col = nt * 16 + mrow;
        float bv = b1[col];
#pragma unroll
        for (int r = 0; r < 4; ++r) {
            int row = m0 + quad * 4 + r;
            if (row < NN)
                outp[(size_t)row * 128 + col] = fmaxf((acc2[nt][r] + bv) * scl[r], 0.0f);
        }
    }
}

extern "C" void kernel_launch(void* const* d_in, const int* in_sizes, int n_in,
                              void* d_out, int out_size, void* d_ws, size_t ws_size,
                              hipStream_t stream) {
    (void)in_sizes; (void)n_in; (void)out_size; (void)ws_size;
    const float* featA = (const float*)d_in[0];
    const float* featB = (const float*)d_in[1];
    const int* dst_aa = (const int*)d_in[3];
    const int* dst_ab = (const int*)d_in[5];
    const int* dst_ba = (const int*)d_in[7];
    const float* Wr0 = (const float*)d_in[10];
    const float* br0 = (const float*)d_in[11];
    const float* Wr1 = (const float*)d_in[16];
    const float* br1 = (const float*)d_in[17];

    char* ws = (char*)d_ws;
    u16* Wt = (u16*)ws;                                  // 4*16384*2 = 128 KB
    unsigned char* masks = (unsigned char*)(ws + 4 * 16384 * 2);  // 3*NN

    hipMemsetAsync(masks, 0, (size_t)3 * NN, stream);
    const int markBlocks = (EE + 255) / 256;             // 1563
    prep<<<markBlocks + 256, 256, 0, stream>>>(dst_aa, dst_ab, dst_ba, masks, Wr0, Wr1, Wt);

    const int blocksPerType = (NN + 127) / 128;          // 782
    fused2<<<2 * blocksPerType, 512, 0, stream>>>(featA, featB, Wt, br0, br1, masks,
                                                  (float*)d_out);
}